// Round 9
// baseline (136.113 us; speedup 1.0000x reference)
//
#include <hip/hip_runtime.h>
#include <hip/hip_bf16.h>

#define NB 8192
#define ND 128

static constexpr float F_ALPHA  = 2.0f;
static constexpr float F_BETA   = 50.0f;
static constexpr float F_BASE   = 0.5f;
static constexpr float F_MARGIN = 0.1f;
static constexpr float LOG2E    = 1.4426950408889634f;
// exp(-A*(s-B)) = exp2(s*C1P + C0P); exp(B*(s-B)) = exp2(s*C1N + C0N)
static constexpr float C1P = -F_ALPHA * LOG2E, C0P =  F_ALPHA * F_BASE * LOG2E;
static constexpr float C1N =  F_BETA  * LOG2E, C0N = -F_BETA  * F_BASE * LOG2E;

typedef __attribute__((ext_vector_type(8))) short short8;
typedef __attribute__((ext_vector_type(4))) float f32x4;

// monotone float<->uint encoding for atomic min/max
__device__ __forceinline__ unsigned fenc(float f) {
  unsigned u = __float_as_uint(f);
  return (u & 0x80000000u) ? ~u : (u | 0x80000000u);
}
__device__ __forceinline__ float fdec(unsigned k) {
  unsigned u = (k & 0x80000000u) ? (k & 0x7FFFFFFFu) : ~k;
  return __uint_as_float(u);
}

__device__ __forceinline__ void async16(const void* g, void* l) {
  __builtin_amdgcn_global_load_lds(
      (const __attribute__((address_space(1))) void*)g,
      (__attribute__((address_space(3))) void*)l, 16, 0, 0);
}

// fp32 -> bf16 convert into MFMA-FRAGMENT-PACKED layout (verified in R6):
// P[g][kk][lane][8 bf16], lane = q*16 + r15 holds E[g*16+r15][kk*32+q*8..+8].
// A wave's fragment load is P + (g*4+kk)*1024 + lane*16 -> ONE coalesced
// global_load_dwordx4 with zero per-lane address math.
__global__ void k_convert(const float4* __restrict__ in, char* __restrict__ P,
                          const int* __restrict__ lab,
                          unsigned* __restrict__ pmKey, unsigned* __restrict__ nmKey,
                          float* __restrict__ pSum, float* __restrict__ nSum,
                          int* __restrict__ cnt) {
  int i = blockIdx.x * 256 + threadIdx.x;   // one float4 = 4 k-elements
  float4 v = in[i];
  __hip_bfloat16 a = __float2bfloat16(v.x), b = __float2bfloat16(v.y),
                 c = __float2bfloat16(v.z), d = __float2bfloat16(v.w);
  ushort4 o;
  o.x = *(unsigned short*)&a; o.y = *(unsigned short*)&b;
  o.z = *(unsigned short*)&c; o.w = *(unsigned short*)&d;
  const int row = i >> 5, c4 = i & 31;      // k0 = c4*4
  const int g = row >> 4, r15 = row & 15;
  const int kk = c4 >> 3, q = (c4 >> 1) & 3, j = (c4 & 1) * 4;
  *(ushort4*)(P + (((g * 4 + kk) * 64 + q * 16 + r15) * 16 + j * 2)) = o;
  if (i < NB) {
    pmKey[i] = 0xFFFFFFFFu;   // atomic-min identity
    nmKey[i] = 0u;            // atomic-max identity
    pSum[i]  = 0.f;
    nSum[i]  = 0.f;
    atomicAdd(&cnt[lab[i]], 1);
  }
}

// Block = 256 threads = 4 waves; 128 rows x 128 cols. Everything is in the
// packed-fragment layout: staging is a LINEAR 32 KB global_load_lds copy;
// every ds_read is sB + lane*16 + COMPILE-TIME offset (one VGPR address,
// conflict-free); A-fragments are coalesced dwordx4 from P. One barrier,
// then a barrier-free global-free inner loop. 32 KB LDS + <=128 VGPR ->
// 4 blocks/CU = 4 waves/SIMD.
// Diagonal: self counts as positive for pos_min (self-sim ~1.0 >= cross
// sims); pair existence from label histogram; pass 0 stores the MFMA-exact
// self-sim; k_final subtracts self's conditional hard-pos term.
template<int PASS>
__global__ __launch_bounds__(256, 4)
void k_simpass(const char* __restrict__ P,
               const int* __restrict__ lab,
               unsigned* __restrict__ pmKey,
               unsigned* __restrict__ nmKey,
               float* __restrict__ pSum,
               float* __restrict__ nSum,
               float* __restrict__ selfSim)
{
  __shared__ __align__(16) char sB[32768];   // 128 cols x 128 K, packed
  __shared__ int sLc[128];

  const int t    = threadIdx.x;
  const int lane = t & 63, wid = t >> 6;
  const int q    = lane >> 4, r15 = lane & 15;
  const int rBase  = blockIdx.y * 128 + wid * 32;   // wave-exclusive 32 rows
  const int cBase0 = blockIdx.x * 128;

  // ---- prologue: LINEAR staged copy of the packed B-chunk ----
  const char* gB = P + (size_t)cBase0 * 256;
#pragma unroll
  for (int ch = 0; ch < 8; ++ch)
    async16(gB + ch * 4096 + t * 16, sB + ch * 4096 + wid * 1024);
  if (t < 128) sLc[t] = lab[cBase0 + t];

  // A fragments: 8 coalesced dwordx4 from P (32 VGPR)
  short8 afr[4][2];   // [kk][mi]
#pragma unroll
  for (int mi = 0; mi < 2; ++mi) {
    const int g = (rBase >> 4) + mi;
#pragma unroll
    for (int kk = 0; kk < 4; ++kk)
      afr[kk][mi] = *(const short8*)(P + (size_t)(g * 4 + kk) * 1024 + lane * 16);
  }

  // per-lane row data (C-rows: mi*16 + q*4 + rg); margins pre-folded
  int lrr[8]; float pmr[8], nmr[8];
#pragma unroll
  for (int mi = 0; mi < 2; ++mi)
#pragma unroll
    for (int rg = 0; rg < 4; ++rg) {
      int r = rBase + mi * 16 + q * 4 + rg;
      lrr[mi * 4 + rg] = lab[r];
      if (PASS == 1) {
        pmr[mi * 4 + rg] = fdec(pmKey[r]) - F_MARGIN;  // hn: s > pm - M
        nmr[mi * 4 + rg] = fdec(nmKey[r]) + F_MARGIN;  // hp: s < nm + M
      }
    }

  float st1[8], st2[8];
#pragma unroll
  for (int i = 0; i < 8; ++i) {
    st1[i] = (PASS == 0) ?  __builtin_inff() : 0.f;
    st2[i] = (PASS == 0) ? -__builtin_inff() : 0.f;
  }

  __syncthreads();   // B-chunk + labels resident; no barriers after this

  const char* sBl = (const char*)sB + lane * 16;  // the ONE ds_read address

#pragma unroll
  for (int ct = 0; ct < 4; ++ct) {
    const int cTile = cBase0 + ct * 32;

    int cl[2];
    cl[0] = sLc[ct * 32 + r15];
    cl[1] = sLc[ct * 32 + 16 + r15];

    f32x4 acc[2][2];
#pragma unroll
    for (int mi = 0; mi < 2; ++mi)
#pragma unroll
      for (int ni = 0; ni < 2; ++ni)
        acc[mi][ni] = (f32x4){0.f, 0.f, 0.f, 0.f};

#pragma unroll
    for (int kk = 0; kk < 4; ++kk) {
      // compile-time offsets: (colgroup)*4096 + kk*1024
      short8 b0 = *(const short8*)(sBl + ((ct * 2 + 0) * 4096 + kk * 1024));
      short8 b1 = *(const short8*)(sBl + ((ct * 2 + 1) * 4096 + kk * 1024));
#pragma unroll
      for (int mi = 0; mi < 2; ++mi) {
        acc[mi][0] = __builtin_amdgcn_mfma_f32_16x16x32_bf16(afr[kk][mi], b0, acc[mi][0], 0, 0, 0);
        acc[mi][1] = __builtin_amdgcn_mfma_f32_16x16x32_bf16(afr[kk][mi], b1, acc[mi][1], 0, 0, 0);
      }
    }

    // branchless fold (self acts as a positive; no diagonal compare)
#pragma unroll
    for (int mi = 0; mi < 2; ++mi)
#pragma unroll
      for (int rg = 0; rg < 4; ++rg) {
        const int idx = mi * 4 + rg;
        const int lr  = lrr[idx];
#pragma unroll
        for (int ni = 0; ni < 2; ++ni) {
          float s = acc[mi][ni][rg];
          bool same = (lr == cl[ni]);
          if (PASS == 0) {
            st1[idx] = fminf(st1[idx], same ? s :  __builtin_inff());
            st2[idx] = fmaxf(st2[idx], same ? -__builtin_inff() : s);
          } else {
            bool hp = same  && (s < nmr[idx]);
            bool hn = !same && (s > pmr[idx]);
            float e = __builtin_amdgcn_exp2f(
                fmaf(s, same ? C1P : C1N, same ? C0P : C0N));
            st1[idx] += hp ? e : 0.f;
            st2[idx] += hn ? e : 0.f;
          }
        }
      }

    // capture MFMA-exact diagonal (wave-uniform branch: 32-aligned tiles)
    if (PASS == 0 && rBase == cTile) {
#pragma unroll
      for (int mi = 0; mi < 2; ++mi)
#pragma unroll
        for (int rg = 0; rg < 4; ++rg) {
          int r = rBase + mi * 16 + q * 4 + rg;
          // col == row requires ni == mi and r15 == q*4+rg
          if (r15 == q * 4 + rg) selfSim[r] = acc[mi][mi][rg];
        }
    }
  }

  // epilogue: rows wave-exclusive -> 16-lane shuffle reduce + one atomic/row
#pragma unroll
  for (int mi = 0; mi < 2; ++mi)
#pragma unroll
    for (int rg = 0; rg < 4; ++rg) {
      const int idx = mi * 4 + rg;
      const int r   = rBase + mi * 16 + q * 4 + rg;
      float v1 = st1[idx], v2 = st2[idx];
      if (PASS == 0) {
#pragma unroll
        for (int d = 1; d < 16; d <<= 1) {
          v1 = fminf(v1, __shfl_xor(v1, d));
          v2 = fmaxf(v2, __shfl_xor(v2, d));
        }
        if (r15 == 0) {
          atomicMin(&pmKey[r], fenc(v1));
          atomicMax(&nmKey[r], fenc(v2));
        }
      } else {
#pragma unroll
        for (int d = 1; d < 16; d <<= 1) {
          v1 += __shfl_xor(v1, d);
          v2 += __shfl_xor(v2, d);
        }
        if (r15 == 0) {
          if (v1 != 0.f) atomicAdd(&pSum[r], v1);
          if (v2 != 0.f) atomicAdd(&nSum[r], v2);
        }
      }
    }
}

__global__ void k_final(const unsigned* __restrict__ pmKey,
                        const unsigned* __restrict__ nmKey,
                        const float* __restrict__ pSum,
                        const float* __restrict__ nSum,
                        const float* __restrict__ selfSim,
                        const int* __restrict__ lab,
                        const int* __restrict__ cnt,
                        float* __restrict__ out)
{
  const int t = threadIdx.x;
  float ls = 0.f, nv = 0.f;
  for (int r = t; r < NB; r += 1024) {
    int c = cnt[lab[r]];
    unsigned nk = nmKey[r];
    bool pe = (c > 1);                 // a true positive pair exists
    bool ne = (c < NB) && (nk > 0x007FFFFFu);
    if (pe && ne) {
      float pm = fdec(pmKey[r]), nm = fdec(nk);
      if (pm - F_MARGIN < nm) {        // hard_pos.any <=> hard_neg.any
        float ss = selfSim[r];
        float psub = (ss - F_MARGIN < nm)
                       ? __builtin_amdgcn_exp2f(fmaf(ss, C1P, C0P)) : 0.f;
        float ps = fmaxf(pSum[r] - psub, 0.f);
        ls += log1pf(ps) * (1.0f / F_ALPHA) + log1pf(nSum[r]) * (1.0f / F_BETA);
        nv += 1.f;
      }
    }
  }
#pragma unroll
  for (int d = 1; d < 64; d <<= 1) {
    ls += __shfl_xor(ls, d);
    nv += __shfl_xor(nv, d);
  }
  __shared__ float sL[16], sC[16];
  if ((t & 63) == 0) { sL[t >> 6] = ls; sC[t >> 6] = nv; }
  __syncthreads();
  if (t == 0) {
    float a = 0.f, c = 0.f;
#pragma unroll
    for (int w = 0; w < 16; ++w) { a += sL[w]; c += sC[w]; }
    out[0] = a / fmaxf(c, 1.f);
  }
}

extern "C" void kernel_launch(void* const* d_in, const int* in_sizes, int n_in,
                              void* d_out, int out_size, void* d_ws, size_t ws_size,
                              hipStream_t stream)
{
  const float* emb = (const float*)d_in[0];
  const int*   lab = (const int*)d_in[1];
  float* out = (float*)d_out;

  char* ws = (char*)d_ws;
  char*     P       = ws;                                       // 2 MB packed
  unsigned* pmKey   = (unsigned*)(ws + 2097152);                // 32 KB
  unsigned* nmKey   = (unsigned*)(ws + 2097152 + 32768);        // 32 KB
  float*    pSum    = (float*)(ws + 2097152 + 65536);           // 32 KB
  float*    nSum    = (float*)(ws + 2097152 + 98304);           // 32 KB
  float*    selfSim = (float*)(ws + 2097152 + 131072);          // 32 KB
  int*      cnt     = (int*)(ws + 2097152 + 163840);            // 2 KB

  hipMemsetAsync(cnt, 0, 512 * sizeof(int), stream);
  k_convert<<<NB * ND / (256 * 4), 256, 0, stream>>>(
      (const float4*)emb, P, lab, pmKey, nmKey, pSum, nSum, cnt);

  dim3 grid(64, 64);   // 64 col-chunks x 64 row-blocks; 256-thread blocks
  k_simpass<0><<<grid, 256, 0, stream>>>(P, lab, pmKey, nmKey, pSum, nSum, selfSim);
  k_simpass<1><<<grid, 256, 0, stream>>>(P, lab, pmKey, nmKey, pSum, nSum, selfSim);
  k_final<<<1, 1024, 0, stream>>>(pmKey, nmKey, pSum, nSum, selfSim, lab, cnt, out);
}

// Round 10
// 124.990 us; speedup vs baseline: 1.0890x; 1.0890x over previous
//
#include <hip/hip_runtime.h>
#include <hip/hip_bf16.h>

#define NB 8192
#define ND 128

static constexpr float F_ALPHA  = 2.0f;
static constexpr float F_BETA   = 50.0f;
static constexpr float F_BASE   = 0.5f;
static constexpr float F_MARGIN = 0.1f;
static constexpr float LOG2E    = 1.4426950408889634f;
// exp(-A*(s-B)) = exp2(s*C1P + C0P); exp(B*(s-B)) = exp2(s*C1N + C0N)
static constexpr float C1P = -F_ALPHA * LOG2E, C0P =  F_ALPHA * F_BASE * LOG2E;
static constexpr float C1N =  F_BETA  * LOG2E, C0N = -F_BETA  * F_BASE * LOG2E;

typedef __attribute__((ext_vector_type(8))) short short8;
typedef __attribute__((ext_vector_type(4))) float f32x4;

// monotone float<->uint encoding for atomic min/max
__device__ __forceinline__ unsigned fenc(float f) {
  unsigned u = __float_as_uint(f);
  return (u & 0x80000000u) ? ~u : (u | 0x80000000u);
}
__device__ __forceinline__ float fdec(unsigned k) {
  unsigned u = (k & 0x80000000u) ? (k & 0x7FFFFFFFu) : ~k;
  return __uint_as_float(u);
}

__device__ __forceinline__ void async16(const void* g, void* l) {
  __builtin_amdgcn_global_load_lds(
      (const __attribute__((address_space(1))) void*)g,
      (__attribute__((address_space(3))) void*)l, 16, 0, 0);
}

// fp32 -> bf16 convert into MFMA-FRAGMENT-PACKED layout (proven R6/R8/R9):
// P[g][kk][lane][8 bf16], lane = q*16 + r15 holds E[g*16+r15][kk*32+q*8..+8].
// A wave's fragment load is P + (g*4+kk)*1024 + lane*16 -> ONE coalesced
// global_load_dwordx4 with zero per-lane address math.
__global__ void k_convert(const float4* __restrict__ in, char* __restrict__ P,
                          const int* __restrict__ lab,
                          unsigned* __restrict__ pmKey, unsigned* __restrict__ nmKey,
                          float* __restrict__ pSum, float* __restrict__ nSum,
                          int* __restrict__ cnt) {
  int i = blockIdx.x * 256 + threadIdx.x;   // one float4 = 4 k-elements
  float4 v = in[i];
  __hip_bfloat16 a = __float2bfloat16(v.x), b = __float2bfloat16(v.y),
                 c = __float2bfloat16(v.z), d = __float2bfloat16(v.w);
  ushort4 o;
  o.x = *(unsigned short*)&a; o.y = *(unsigned short*)&b;
  o.z = *(unsigned short*)&c; o.w = *(unsigned short*)&d;
  const int row = i >> 5, c4 = i & 31;      // k0 = c4*4
  const int g = row >> 4, r15 = row & 15;
  const int kk = c4 >> 3, q = (c4 >> 1) & 3, j = (c4 & 1) * 4;
  *(ushort4*)(P + (((g * 4 + kk) * 64 + q * 16 + r15) * 16 + j * 2)) = o;
  if (i < NB) {
    pmKey[i] = 0xFFFFFFFFu;   // atomic-min identity
    nmKey[i] = 0u;            // atomic-max identity
    pSum[i]  = 0.f;
    nSum[i]  = 0.f;
    atomicAdd(&cnt[lab[i]], 1);
  }
}

// Block = 512 threads = 8 waves; 128 rows x 128 cols. Wave = ONE 16-row
// strip (small state: afr 16 + acc 8 + st 8 + consts ~12 regs -> no spill).
// Packed layout everywhere: staging is a linear 32 KB copy; every ds_read
// is ONE address + compile-time-ish offset, conflict-free. 33 KB LDS ->
// 4 blocks/CU = up to 8 waves/SIMD: latency hidden by TLP.
// Diagonal: self counts as positive for pos_min (self-sim ~1.0 >= cross
// sims); pair existence from label histogram; pass 0 stores the MFMA-exact
// self-sim; k_final subtracts self's conditional hard-pos term.
template<int PASS>
__global__ __launch_bounds__(512, 4)
void k_simpass(const char* __restrict__ P,
               const int* __restrict__ lab,
               unsigned* __restrict__ pmKey,
               unsigned* __restrict__ nmKey,
               float* __restrict__ pSum,
               float* __restrict__ nSum,
               float* __restrict__ selfSim)
{
  __shared__ __align__(16) char sB[32768];   // 128 cols x 128 K, packed
  __shared__ int sLc[128];

  const int t    = threadIdx.x;
  const int lane = t & 63, wid = t >> 6;
  const int q    = lane >> 4, r15 = lane & 15;
  const int rBase  = blockIdx.y * 128 + wid * 16;   // wave-exclusive 16 rows
  const int cBase0 = blockIdx.x * 128;

  // ---- prologue: LINEAR staged copy of the packed B-chunk ----
  const char* gB = P + (size_t)cBase0 * 256;
#pragma unroll
  for (int ch = 0; ch < 4; ++ch)
    async16(gB + ch * 8192 + t * 16, sB + ch * 8192 + wid * 1024);
  if (t < 128) sLc[t] = lab[cBase0 + t];

  // A fragments: 4 coalesced dwordx4 from P (16 VGPR), wave-invariant
  short8 afr[4];   // [kk]
  {
    const char* pa = P + (size_t)(rBase >> 4) * 4096 + lane * 16;
#pragma unroll
    for (int kk = 0; kk < 4; ++kk)
      afr[kk] = *(const short8*)(pa + kk * 1024);
  }

  // per-lane row data (C-rows: q*4 + rg); margins pre-folded
  int lrr[4]; float pmr[4], nmr[4];
#pragma unroll
  for (int rg = 0; rg < 4; ++rg) {
    int r = rBase + q * 4 + rg;
    lrr[rg] = lab[r];
    if (PASS == 1) {
      pmr[rg] = fdec(pmKey[r]) - F_MARGIN;  // hn: s > pm - M
      nmr[rg] = fdec(nmKey[r]) + F_MARGIN;  // hp: s < nm + M
    }
  }

  float st1[4], st2[4];
#pragma unroll
  for (int i = 0; i < 4; ++i) {
    st1[i] = (PASS == 0) ?  __builtin_inff() : 0.f;
    st2[i] = (PASS == 0) ? -__builtin_inff() : 0.f;
  }

  __syncthreads();   // B-chunk + labels resident; no barriers after this

  const char* sBl = (const char*)sB + lane * 16;  // the ONE ds_read address

#pragma unroll 1   // keep live set flat; TLP (not ILP) hides latency
  for (int ct = 0; ct < 4; ++ct) {
    const int cTile = cBase0 + ct * 32;
    const char* sBt = sBl + ct * 8192;

    int cl[2];
    cl[0] = sLc[ct * 32 + r15];
    cl[1] = sLc[ct * 32 + 16 + r15];

    f32x4 acc[2];
    acc[0] = (f32x4){0.f, 0.f, 0.f, 0.f};
    acc[1] = (f32x4){0.f, 0.f, 0.f, 0.f};

#pragma unroll
    for (int kk = 0; kk < 4; ++kk) {
      short8 b0 = *(const short8*)(sBt + kk * 1024);
      short8 b1 = *(const short8*)(sBt + 4096 + kk * 1024);
      acc[0] = __builtin_amdgcn_mfma_f32_16x16x32_bf16(afr[kk], b0, acc[0], 0, 0, 0);
      acc[1] = __builtin_amdgcn_mfma_f32_16x16x32_bf16(afr[kk], b1, acc[1], 0, 0, 0);
    }

    // branchless fold (self acts as a positive; no diagonal compare)
#pragma unroll
    for (int rg = 0; rg < 4; ++rg) {
      const int lr = lrr[rg];
#pragma unroll
      for (int ni = 0; ni < 2; ++ni) {
        float s = acc[ni][rg];
        bool same = (lr == cl[ni]);
        if (PASS == 0) {
          st1[rg] = fminf(st1[rg], same ? s :  __builtin_inff());
          st2[rg] = fmaxf(st2[rg], same ? -__builtin_inff() : s);
        } else {
          bool hp = same  && (s < nmr[rg]);
          bool hn = !same && (s > pmr[rg]);
          float e = __builtin_amdgcn_exp2f(
              fmaf(s, same ? C1P : C1N, same ? C0P : C0N));
          st1[rg] += hp ? e : 0.f;
          st2[rg] += hn ? e : 0.f;
        }
      }
    }

    // capture MFMA-exact diagonal (wave-uniform outer branch)
    if (PASS == 0 && (unsigned)(rBase - cTile) < 32u) {
      const int nid = (rBase >> 4) & 1;   // which 16-col group is diagonal
#pragma unroll
      for (int rg = 0; rg < 4; ++rg)
        if (r15 == q * 4 + rg) selfSim[rBase + q * 4 + rg] = acc[nid][rg];
    }
  }

  // epilogue: rows wave-exclusive -> 16-lane shuffle reduce + one atomic/row
#pragma unroll
  for (int rg = 0; rg < 4; ++rg) {
    const int r = rBase + q * 4 + rg;
    float v1 = st1[rg], v2 = st2[rg];
    if (PASS == 0) {
#pragma unroll
      for (int d = 1; d < 16; d <<= 1) {
        v1 = fminf(v1, __shfl_xor(v1, d));
        v2 = fmaxf(v2, __shfl_xor(v2, d));
      }
      if (r15 == 0) {
        atomicMin(&pmKey[r], fenc(v1));
        atomicMax(&nmKey[r], fenc(v2));
      }
    } else {
#pragma unroll
      for (int d = 1; d < 16; d <<= 1) {
        v1 += __shfl_xor(v1, d);
        v2 += __shfl_xor(v2, d);
      }
      if (r15 == 0) {
        if (v1 != 0.f) atomicAdd(&pSum[r], v1);
        if (v2 != 0.f) atomicAdd(&nSum[r], v2);
      }
    }
  }
}

__global__ void k_final(const unsigned* __restrict__ pmKey,
                        const unsigned* __restrict__ nmKey,
                        const float* __restrict__ pSum,
                        const float* __restrict__ nSum,
                        const float* __restrict__ selfSim,
                        const int* __restrict__ lab,
                        const int* __restrict__ cnt,
                        float* __restrict__ out)
{
  const int t = threadIdx.x;
  float ls = 0.f, nv = 0.f;
  for (int r = t; r < NB; r += 1024) {
    int c = cnt[lab[r]];
    unsigned nk = nmKey[r];
    bool pe = (c > 1);                 // a true positive pair exists
    bool ne = (c < NB) && (nk > 0x007FFFFFu);
    if (pe && ne) {
      float pm = fdec(pmKey[r]), nm = fdec(nk);
      if (pm - F_MARGIN < nm) {        // hard_pos.any <=> hard_neg.any
        float ss = selfSim[r];
        float psub = (ss - F_MARGIN < nm)
                       ? __builtin_amdgcn_exp2f(fmaf(ss, C1P, C0P)) : 0.f;
        float ps = fmaxf(pSum[r] - psub, 0.f);
        ls += log1pf(ps) * (1.0f / F_ALPHA) + log1pf(nSum[r]) * (1.0f / F_BETA);
        nv += 1.f;
      }
    }
  }
#pragma unroll
  for (int d = 1; d < 64; d <<= 1) {
    ls += __shfl_xor(ls, d);
    nv += __shfl_xor(nv, d);
  }
  __shared__ float sL[16], sC[16];
  if ((t & 63) == 0) { sL[t >> 6] = ls; sC[t >> 6] = nv; }
  __syncthreads();
  if (t == 0) {
    float a = 0.f, c = 0.f;
#pragma unroll
    for (int w = 0; w < 16; ++w) { a += sL[w]; c += sC[w]; }
    out[0] = a / fmaxf(c, 1.f);
  }
}

extern "C" void kernel_launch(void* const* d_in, const int* in_sizes, int n_in,
                              void* d_out, int out_size, void* d_ws, size_t ws_size,
                              hipStream_t stream)
{
  const float* emb = (const float*)d_in[0];
  const int*   lab = (const int*)d_in[1];
  float* out = (float*)d_out;

  char* ws = (char*)d_ws;
  char*     P       = ws;                                       // 2 MB packed
  unsigned* pmKey   = (unsigned*)(ws + 2097152);                // 32 KB
  unsigned* nmKey   = (unsigned*)(ws + 2097152 + 32768);        // 32 KB
  float*    pSum    = (float*)(ws + 2097152 + 65536);           // 32 KB
  float*    nSum    = (float*)(ws + 2097152 + 98304);           // 32 KB
  float*    selfSim = (float*)(ws + 2097152 + 131072);          // 32 KB
  int*      cnt     = (int*)(ws + 2097152 + 163840);            // 2 KB

  hipMemsetAsync(cnt, 0, 512 * sizeof(int), stream);
  k_convert<<<NB * ND / (256 * 4), 256, 0, stream>>>(
      (const float4*)emb, P, lab, pmKey, nmKey, pSum, nSum, cnt);

  dim3 grid(64, 64);   // 64 col-chunks x 64 row-blocks; 512-thread blocks
  k_simpass<0><<<grid, 512, 0, stream>>>(P, lab, pmKey, nmKey, pSum, nSum, selfSim);
  k_simpass<1><<<grid, 512, 0, stream>>>(P, lab, pmKey, nmKey, pSum, nSum, selfSim);
  k_final<<<1, 1024, 0, stream>>>(pmKey, nmKey, pSum, nSum, selfSim, lab, cnt, out);
}

// Round 11
// 100.975 us; speedup vs baseline: 1.3480x; 1.2378x over previous
//
#include <hip/hip_runtime.h>
#include <hip/hip_bf16.h>

#define NB 8192
#define ND 128

static constexpr float F_ALPHA  = 2.0f;
static constexpr float F_BETA   = 50.0f;
static constexpr float F_BASE   = 0.5f;
static constexpr float F_MARGIN = 0.1f;
static constexpr float LOG2E    = 1.4426950408889634f;
// exp(-A*(s-B)) = exp2(s*C1P + C0P); exp(B*(s-B)) = exp2(s*C1N + C0N)
static constexpr float C1P = -F_ALPHA * LOG2E, C0P =  F_ALPHA * F_BASE * LOG2E;
static constexpr float C1N =  F_BETA  * LOG2E, C0N = -F_BETA  * F_BASE * LOG2E;

typedef __attribute__((ext_vector_type(8))) short short8;
typedef __attribute__((ext_vector_type(4))) float f32x4;

// monotone float<->uint encoding for atomic min/max
__device__ __forceinline__ unsigned fenc(float f) {
  unsigned u = __float_as_uint(f);
  return (u & 0x80000000u) ? ~u : (u | 0x80000000u);
}
__device__ __forceinline__ float fdec(unsigned k) {
  unsigned u = (k & 0x80000000u) ? (k & 0x7FFFFFFFu) : ~k;
  return __uint_as_float(u);
}

// fp32 -> bf16 convert into MFMA-FRAGMENT-PACKED layout (proven R6/R9/R10):
// P[g][kk][lane][8 bf16], lane = q*16 + r15 holds E[g*16+r15][kk*32+q*8..+8].
// A wave's fragment load is P + ((g*4+kk)*64 + lane)*16 -> ONE coalesced
// global_load_dwordx4 with zero per-lane address math.
__global__ void k_convert(const float4* __restrict__ in, char* __restrict__ P,
                          const int* __restrict__ lab,
                          unsigned* __restrict__ pmKey, unsigned* __restrict__ nmKey,
                          float* __restrict__ pSum, float* __restrict__ nSum,
                          int* __restrict__ cnt) {
  int i = blockIdx.x * 256 + threadIdx.x;   // one float4 = 4 k-elements
  float4 v = in[i];
  __hip_bfloat16 a = __float2bfloat16(v.x), b = __float2bfloat16(v.y),
                 c = __float2bfloat16(v.z), d = __float2bfloat16(v.w);
  ushort4 o;
  o.x = *(unsigned short*)&a; o.y = *(unsigned short*)&b;
  o.z = *(unsigned short*)&c; o.w = *(unsigned short*)&d;
  const int row = i >> 5, c4 = i & 31;      // k0 = c4*4
  const int g = row >> 4, r15 = row & 15;
  const int kk = c4 >> 3, q = (c4 >> 1) & 3, j = (c4 & 1) * 4;
  *(ushort4*)(P + (((g * 4 + kk) * 64 + q * 16 + r15) * 16 + j * 2)) = o;
  if (i < NB) {
    pmKey[i] = 0xFFFFFFFFu;   // atomic-min identity
    nmKey[i] = 0u;            // atomic-max identity
    pSum[i]  = 0.f;
    nSum[i]  = 0.f;
    atomicAdd(&cnt[lab[i]], 1);
  }
}

// ZERO LDS, ZERO barriers: no block-wide phase-lock. Each wave owns 32 rows
// x 512 cols and streams 16 col-tiles of 32 directly from the packed buffer
// (every A/B load = ONE coalesced dwordx4, L2/L1-resident). 4 waves/block
// share each col-tile through L1. ~115 VGPR under the (256,2)=128 cap ->
// 16 waves/CU; TLP + per-tile ILP hide the L2 latency.
// Diagonal: self counts as positive for pos_min (self-sim ~1.0 >= cross
// sims); pair existence from label histogram; pass 0 stores the MFMA-exact
// self-sim; k_final subtracts self's conditional hard-pos term.
template<int PASS>
__global__ __launch_bounds__(256, 2)
void k_simpass(const char* __restrict__ P,
               const int* __restrict__ lab,
               unsigned* __restrict__ pmKey,
               unsigned* __restrict__ nmKey,
               float* __restrict__ pSum,
               float* __restrict__ nSum,
               float* __restrict__ selfSim)
{
  const int t    = threadIdx.x;
  const int lane = t & 63, wid = t >> 6;
  const int q    = lane >> 4, r15 = lane & 15;
  const int rBase = blockIdx.y * 128 + wid * 32;   // wave-exclusive 32 rows
  const int cBase = blockIdx.x * 512;

  // A fragments: 2 row-groups x 4 kk -> 8 coalesced dwordx4 (32 VGPR)
  short8 afr[4][2];
#pragma unroll
  for (int mi = 0; mi < 2; ++mi) {
    const char* pa = P + (size_t)(((rBase >> 4) + mi) * 4) * 1024 + lane * 16;
#pragma unroll
    for (int kk = 0; kk < 4; ++kk)
      afr[kk][mi] = *(const short8*)(pa + kk * 1024);
  }

  // per-lane row data (C-rows: mi*16 + q*4 + rg); margins pre-folded
  int lrr[8]; float pmr[8], nmr[8];
#pragma unroll
  for (int mi = 0; mi < 2; ++mi)
#pragma unroll
    for (int rg = 0; rg < 4; ++rg) {
      int r = rBase + mi * 16 + q * 4 + rg;
      lrr[mi * 4 + rg] = lab[r];
      if (PASS == 1) {
        pmr[mi * 4 + rg] = fdec(pmKey[r]) - F_MARGIN;  // hn: s > pm - M
        nmr[mi * 4 + rg] = fdec(nmKey[r]) + F_MARGIN;  // hp: s < nm + M
      }
    }

  float st1[8], st2[8];
#pragma unroll
  for (int i = 0; i < 8; ++i) {
    st1[i] = (PASS == 0) ?  __builtin_inff() : 0.f;
    st2[i] = (PASS == 0) ? -__builtin_inff() : 0.f;
  }

#pragma unroll 1   // flat live set; TLP hides per-tile latency
  for (int ct = 0; ct < 16; ++ct) {
    const int cTile = cBase + ct * 32;
    const char* pb = P + (size_t)((cTile >> 4) * 4) * 1024 + lane * 16;

    int cl[2];
    cl[0] = lab[cTile + r15];
    cl[1] = lab[cTile + 16 + r15];

    f32x4 acc[2][2];
#pragma unroll
    for (int mi = 0; mi < 2; ++mi) {
      acc[mi][0] = (f32x4){0.f, 0.f, 0.f, 0.f};
      acc[mi][1] = (f32x4){0.f, 0.f, 0.f, 0.f};
    }

#pragma unroll
    for (int kk = 0; kk < 4; ++kk) {
      short8 b0 = *(const short8*)(pb + kk * 1024);           // col group 0
      short8 b1 = *(const short8*)(pb + 4096 + kk * 1024);    // col group 1
#pragma unroll
      for (int mi = 0; mi < 2; ++mi) {
        acc[mi][0] = __builtin_amdgcn_mfma_f32_16x16x32_bf16(afr[kk][mi], b0, acc[mi][0], 0, 0, 0);
        acc[mi][1] = __builtin_amdgcn_mfma_f32_16x16x32_bf16(afr[kk][mi], b1, acc[mi][1], 0, 0, 0);
      }
    }

    // branchless fold (self acts as a positive; no diagonal compare)
#pragma unroll
    for (int mi = 0; mi < 2; ++mi)
#pragma unroll
      for (int rg = 0; rg < 4; ++rg) {
        const int idx = mi * 4 + rg;
        const int lr  = lrr[idx];
#pragma unroll
        for (int ni = 0; ni < 2; ++ni) {
          float s = acc[mi][ni][rg];
          bool same = (lr == cl[ni]);
          if (PASS == 0) {
            st1[idx] = fminf(st1[idx], same ? s :  __builtin_inff());
            st2[idx] = fmaxf(st2[idx], same ? -__builtin_inff() : s);
          } else {
            bool hp = same  && (s < nmr[idx]);
            bool hn = !same && (s > pmr[idx]);
            float e = __builtin_amdgcn_exp2f(
                fmaf(s, same ? C1P : C1N, same ? C0P : C0N));
            st1[idx] += hp ? e : 0.f;
            st2[idx] += hn ? e : 0.f;
          }
        }
      }

    // capture MFMA-exact diagonal (wave-uniform branch; rBase is 32-aligned
    // so the diagonal of this wave's rows is exactly the tile cTile==rBase)
    if (PASS == 0 && cTile == rBase) {
#pragma unroll
      for (int mi = 0; mi < 2; ++mi)
#pragma unroll
        for (int rg = 0; rg < 4; ++rg)
          if (r15 == q * 4 + rg)
            selfSim[rBase + mi * 16 + q * 4 + rg] = acc[mi][mi][rg];
    }
  }

  // epilogue: rows wave-exclusive -> 16-lane shuffle reduce + one atomic/row
#pragma unroll
  for (int mi = 0; mi < 2; ++mi)
#pragma unroll
    for (int rg = 0; rg < 4; ++rg) {
      const int idx = mi * 4 + rg;
      const int r   = rBase + mi * 16 + q * 4 + rg;
      float v1 = st1[idx], v2 = st2[idx];
      if (PASS == 0) {
#pragma unroll
        for (int d = 1; d < 16; d <<= 1) {
          v1 = fminf(v1, __shfl_xor(v1, d));
          v2 = fmaxf(v2, __shfl_xor(v2, d));
        }
        if (r15 == 0) {
          atomicMin(&pmKey[r], fenc(v1));
          atomicMax(&nmKey[r], fenc(v2));
        }
      } else {
#pragma unroll
        for (int d = 1; d < 16; d <<= 1) {
          v1 += __shfl_xor(v1, d);
          v2 += __shfl_xor(v2, d);
        }
        if (r15 == 0) {
          if (v1 != 0.f) atomicAdd(&pSum[r], v1);
          if (v2 != 0.f) atomicAdd(&nSum[r], v2);
        }
      }
    }
}

__global__ void k_final(const unsigned* __restrict__ pmKey,
                        const unsigned* __restrict__ nmKey,
                        const float* __restrict__ pSum,
                        const float* __restrict__ nSum,
                        const float* __restrict__ selfSim,
                        const int* __restrict__ lab,
                        const int* __restrict__ cnt,
                        float* __restrict__ out)
{
  const int t = threadIdx.x;
  float ls = 0.f, nv = 0.f;
  for (int r = t; r < NB; r += 1024) {
    int c = cnt[lab[r]];
    unsigned nk = nmKey[r];
    bool pe = (c > 1);                 // a true positive pair exists
    bool ne = (c < NB) && (nk > 0x007FFFFFu);
    if (pe && ne) {
      float pm = fdec(pmKey[r]), nm = fdec(nk);
      if (pm - F_MARGIN < nm) {        // hard_pos.any <=> hard_neg.any
        float ss = selfSim[r];
        float psub = (ss - F_MARGIN < nm)
                       ? __builtin_amdgcn_exp2f(fmaf(ss, C1P, C0P)) : 0.f;
        float ps = fmaxf(pSum[r] - psub, 0.f);
        ls += log1pf(ps) * (1.0f / F_ALPHA) + log1pf(nSum[r]) * (1.0f / F_BETA);
        nv += 1.f;
      }
    }
  }
#pragma unroll
  for (int d = 1; d < 64; d <<= 1) {
    ls += __shfl_xor(ls, d);
    nv += __shfl_xor(nv, d);
  }
  __shared__ float sL[16], sC[16];
  if ((t & 63) == 0) { sL[t >> 6] = ls; sC[t >> 6] = nv; }
  __syncthreads();
  if (t == 0) {
    float a = 0.f, c = 0.f;
#pragma unroll
    for (int w = 0; w < 16; ++w) { a += sL[w]; c += sC[w]; }
    out[0] = a / fmaxf(c, 1.f);
  }
}

extern "C" void kernel_launch(void* const* d_in, const int* in_sizes, int n_in,
                              void* d_out, int out_size, void* d_ws, size_t ws_size,
                              hipStream_t stream)
{
  const float* emb = (const float*)d_in[0];
  const int*   lab = (const int*)d_in[1];
  float* out = (float*)d_out;

  char* ws = (char*)d_ws;
  char*     P       = ws;                                       // 2 MB packed
  unsigned* pmKey   = (unsigned*)(ws + 2097152);                // 32 KB
  unsigned* nmKey   = (unsigned*)(ws + 2097152 + 32768);        // 32 KB
  float*    pSum    = (float*)(ws + 2097152 + 65536);           // 32 KB
  float*    nSum    = (float*)(ws + 2097152 + 98304);           // 32 KB
  float*    selfSim = (float*)(ws + 2097152 + 131072);          // 32 KB
  int*      cnt     = (int*)(ws + 2097152 + 163840);            // 2 KB

  hipMemsetAsync(cnt, 0, 512 * sizeof(int), stream);
  k_convert<<<NB * ND / (256 * 4), 256, 0, stream>>>(
      (const float4*)emb, P, lab, pmKey, nmKey, pSum, nSum, cnt);

  dim3 grid(16, 64);   // 16 col-chunks x 64 row-blocks; 256-thread blocks
  k_simpass<0><<<grid, 256, 0, stream>>>(P, lab, pmKey, nmKey, pSum, nSum, selfSim);
  k_simpass<1><<<grid, 256, 0, stream>>>(P, lab, pmKey, nmKey, pSum, nSum, selfSim);
  k_final<<<1, 1024, 0, stream>>>(pmKey, nmKey, pSum, nSum, selfSim, lab, cnt, out);
}